// Round 14
// baseline (68.142 us; speedup 1.0000x reference)
//
#include <hip/hip_runtime.h>
#include <math.h>

#define D_MODEL 4096
#define NE 64
#define TPB 64                 // tokens per block
#define NSTEPS 32              // 4096 k / 128 k-per-step
#define WS_SHORTS (256 * 2 * 64 * 8)   // 262144 shorts per (hi|lo) region

typedef __attribute__((ext_vector_type(8))) short short8;
typedef __attribute__((ext_vector_type(16))) float f32x16;

__device__ __forceinline__ void gl_lds(const void* g, void* l) {
    __builtin_amdgcn_global_load_lds(
        (const __attribute__((address_space(1))) unsigned*)g,
        (__attribute__((address_space(3))) unsigned*)l, 16, 0, 0);
}

// Split 8 fp32 -> bf16 hi (RN) + bf16 lo (truncated residual), perm-packed.
__device__ __forceinline__ void split8(const float4& a, const float4& c,
                                       short8& h8, short8& l8) {
    union { short8 s; unsigned u[4]; } H, L;
    float vv[8] = {a.x, a.y, a.z, a.w, c.x, c.y, c.z, c.w};
#pragma unroll
    for (int p = 0; p < 4; p++) {
        const float v0 = vv[2*p], v1 = vv[2*p+1];
        const unsigned u0 = __float_as_uint(v0), u1 = __float_as_uint(v1);
        const unsigned r0 = u0 + 0x7fffu + ((u0 >> 16) & 1u);
        const unsigned r1 = u1 + 0x7fffu + ((u1 >> 16) & 1u);
        const float lo0 = v0 - __uint_as_float(r0 & 0xffff0000u);
        const float lo1 = v1 - __uint_as_float(r1 & 0xffff0000u);
        H.u[p] = __builtin_amdgcn_perm(r1, r0, 0x07060302u);
        L.u[p] = __builtin_amdgcn_perm(__float_as_uint(lo1),
                                       __float_as_uint(lo0), 0x07060302u);
    }
    h8 = H.s; l8 = L.s;
}

// Pre-split W -> ws bf16 hi/lo, fragment-linear:
// hi[((ck*2+nt)*64+l)*8+j] = bf16(W[nt*32+(l&31)][ck*16+(l>>5)*8+j]), lo at +WS_SHORTS
__global__ void wsplit_kernel(const float* __restrict__ W, short* __restrict__ wsp) {
    const int ck = blockIdx.x, t = threadIdx.x;
    const int nt = t >> 6, l = t & 63;
    const float* wp = W + (size_t)(nt * 32 + (l & 31)) * D_MODEL + ck * 16 + (l >> 5) * 8;
    float4 a = *(const float4*)wp, c = *(const float4*)(wp + 4);
    union { short8 s; unsigned u[4]; } H, L;
    float vv[8] = {a.x, a.y, a.z, a.w, c.x, c.y, c.z, c.w};
#pragma unroll
    for (int p = 0; p < 4; p++) {
        const float v0 = vv[2*p], v1 = vv[2*p+1];
        const unsigned u0 = __float_as_uint(v0), u1 = __float_as_uint(v1);
        const unsigned r0 = u0 + 0x7fffu + ((u0 >> 16) & 1u);
        const unsigned r1 = u1 + 0x7fffu + ((u1 >> 16) & 1u);
        const float lo0 = v0 - __uint_as_float(r0 & 0xffff0000u);
        const float lo1 = v1 - __uint_as_float(r1 & 0xffff0000u);
        const unsigned q0 = __float_as_uint(lo0) + 0x7fffu + ((__float_as_uint(lo0) >> 16) & 1u);
        const unsigned q1 = __float_as_uint(lo1) + 0x7fffu + ((__float_as_uint(lo1) >> 16) & 1u);
        H.u[p] = __builtin_amdgcn_perm(r1, r0, 0x07060302u);
        L.u[p] = __builtin_amdgcn_perm(q1, q0, 0x07060302u);
    }
    const size_t off = ((size_t)(ck * 2 + nt) * 64 + l) * 8;
    *(short8*)(wsp + off)             = H.s;
    *(short8*)(wsp + WS_SHORTS + off) = L.s;
}

#define MF(A_, B_, n_) acc[n_] = __builtin_amdgcn_mfma_f32_32x32x16_bf16( \
                             A_, B_, acc[n_], 0, 0, 0)

// Barrier-free main loop: each wave stages its OWN 32 rows x 128 B per step
// (8 lanes/row -> contiguous 128B segments, coalesced) into a private 4x4KB
// LDS ring; W straight to regs; per-wave counted vmcnt(16); waves drift.
__global__ __launch_bounds__(512, 2) void router_pipe(
    const float* __restrict__ x, const short* __restrict__ wsp,
    const float* __restrict__ b, float* __restrict__ out, int T)
{
    __shared__ char smem[131072];   // 8 waves x 16 KB private rings; epilogue reuse

    const int tid  = threadIdx.x;
    const int wv   = tid >> 6, lane = tid & 63;
    const int mt   = wv & 1;          // token half-tile (32 rows)
    const int kq   = wv >> 1;         // 32-k quarter of the 128-k step
    const int tok0 = blockIdx.x * TPB;

    char* const wbuf = smem + wv * 16384;   // private ring: 4 buffers x 4 KB

    // staging source (per-lane): instruction i covers rows i*8+(lane>>3),
    // chunk col XOR-swizzled: c_src = (lane&7) ^ (lane>>3)  [rule #21]
    const char* gxl = (const char*)x
        + (size_t)(tok0 + mt * 32 + (lane >> 3)) * 16384
        + kq * 128 + (((lane & 7) ^ (lane >> 3)) * 16);

#define STAGEX(s_, bi_) do { char* db_ = wbuf + (bi_) * 4096;                  \
        const char* g_ = gxl + (size_t)(s_) * 512;                             \
        gl_lds(g_,          db_);                                              \
        gl_lds(g_ + 131072, db_ + 1024);                                       \
        gl_lds(g_ + 262144, db_ + 2048);                                       \
        gl_lds(g_ + 393216, db_ + 3072);                                       \
        __builtin_amdgcn_sched_barrier(0); } while (0)

    // W fragments straight to regs: 2 k16-chunks (ck=0,1) x 4 short8 per step.
#define LDW(s_, W0_,W1_,W2_,W3_,W4_,W5_,W6_,W7_) do {                          \
        const size_t cg0_ = (size_t)(s_) * 8 + kq * 2;                         \
        const size_t a0_ = ((cg0_ * 2 + 0) * 64 + lane) * 8;                   \
        const size_t a1_ = ((cg0_ * 2 + 1) * 64 + lane) * 8;                   \
        const size_t a2_ = (((cg0_ + 1) * 2 + 0) * 64 + lane) * 8;             \
        const size_t a3_ = (((cg0_ + 1) * 2 + 1) * 64 + lane) * 8;             \
        W0_ = *(const short8*)(wsp + a0_);                                     \
        W1_ = *(const short8*)(wsp + a1_);                                     \
        W2_ = *(const short8*)(wsp + WS_SHORTS + a0_);                         \
        W3_ = *(const short8*)(wsp + WS_SHORTS + a1_);                         \
        W4_ = *(const short8*)(wsp + a2_);                                     \
        W5_ = *(const short8*)(wsp + a3_);                                     \
        W6_ = *(const short8*)(wsp + WS_SHORTS + a2_);                         \
        W7_ = *(const short8*)(wsp + WS_SHORTS + a3_);                         \
        __builtin_amdgcn_sched_barrier(0); } while (0)

#define FENCE(n_) do { asm volatile("s_waitcnt vmcnt(" #n_ ")" ::: "memory");  \
        __builtin_amdgcn_sched_barrier(0); } while (0)

    f32x16 acc[2];
#pragma unroll
    for (int e = 0; e < 16; e++) { acc[0][e] = 0.f; acc[1][e] = 0.f; }

    // fragment read offsets (bytes within this wave's 4 KB buffer)
    const int rw = lane & 31, khalf = lane >> 5;
    const int rbase = (rw >> 3) * 1024 + (rw & 7) * 128;
#define XO(ck_, j_) (rbase + (((((ck_) * 4) + khalf * 2 + (j_)) ^ (rw & 7)) * 16))
    const int xoA0 = XO(0, 0), xoA1 = XO(0, 1);
    const int xoB0 = XO(1, 0), xoB1 = XO(1, 1);

#define COMPUTE(bi_, W0_,W1_,W2_,W3_,W4_,W5_,W6_,W7_) do {                     \
        const char* buf_ = wbuf + (bi_) * 4096;                                \
        { float4 xa_ = *(const float4*)(buf_ + xoA0);                          \
          float4 xb_ = *(const float4*)(buf_ + xoA1);                          \
          short8 Ah_, Al_; split8(xa_, xb_, Ah_, Al_);                         \
          MF(Ah_, W0_, 0); MF(Ah_, W2_, 0); MF(Al_, W0_, 0); MF(Al_, W2_, 0);  \
          MF(Ah_, W1_, 1); MF(Ah_, W3_, 1); MF(Al_, W1_, 1); MF(Al_, W3_, 1); }\
        { float4 xa_ = *(const float4*)(buf_ + xoB0);                          \
          float4 xb_ = *(const float4*)(buf_ + xoB1);                          \
          short8 Ah_, Al_; split8(xa_, xb_, Ah_, Al_);                         \
          MF(Ah_, W4_, 0); MF(Ah_, W6_, 0); MF(Al_, W4_, 0); MF(Al_, W6_, 0);  \
          MF(Ah_, W5_, 1); MF(Ah_, W7_, 1); MF(Al_, W5_, 1); MF(Al_, W7_, 1); }\
        } while (0)

    short8 Wa0, Wa1, Wa2, Wa3, Wa4, Wa5, Wa6, Wa7;
    short8 Wb0, Wb1, Wb2, Wb3, Wb4, Wb5, Wb6, Wb7;

    // prologue (per-wave FIFO): [x0(4), x1(4), W0(8)] = 16 outstanding
    STAGEX(0, 0); STAGEX(1, 1);
    LDW(0, Wa0,Wa1,Wa2,Wa3,Wa4,Wa5,Wa6,Wa7);

    for (int t = 0; t < NSTEPS - 2; t += 2) {
        LDW(t + 1, Wb0,Wb1,Wb2,Wb3,Wb4,Wb5,Wb6,Wb7);
        STAGEX(t + 2, (t + 2) & 3);
        FENCE(16);                     // drains through x(t)+W(t); keeps x(t+1),W(t+1),x(t+2)
        COMPUTE(t & 3, Wa0,Wa1,Wa2,Wa3,Wa4,Wa5,Wa6,Wa7);
        LDW(t + 2, Wa0,Wa1,Wa2,Wa3,Wa4,Wa5,Wa6,Wa7);
        STAGEX(t + 3, (t + 3) & 3);
        FENCE(16);
        COMPUTE((t + 1) & 3, Wb0,Wb1,Wb2,Wb3,Wb4,Wb5,Wb6,Wb7);
    }
    // tail: steps 30, 31. FIFO entering: [x30(4), W30(8), x31(4)]
    LDW(NSTEPS - 1, Wb0,Wb1,Wb2,Wb3,Wb4,Wb5,Wb6,Wb7);
    FENCE(12);                         // drains x30+W30; keeps x31, W31
    COMPUTE((NSTEPS - 2) & 3, Wa0,Wa1,Wa2,Wa3,Wa4,Wa5,Wa6,Wa7);
    FENCE(0);
    COMPUTE((NSTEPS - 1) & 3, Wb0,Wb1,Wb2,Wb3,Wb4,Wb5,Wb6,Wb7);

    __syncthreads();   // single block-wide sync before reduction

    // ---- reduce 4 k-quarters per mt (2 rounds, rotate-swizzled slabs; 32 KB)
    float* red = (float*)smem;
    auto store_slab = [&](int slab) {
        float* sl = red + ((size_t)slab * 64 + lane) * 32;
#pragma unroll
        for (int q = 0; q < 8; q++) {
            const int nt = q >> 2, rg = (q & 3) * 4;
            *(float4*)(sl + ((q + lane) & 7) * 4) =
                make_float4(acc[nt][rg], acc[nt][rg+1], acc[nt][rg+2], acc[nt][rg+3]);
        }
    };
    auto add_slab = [&](int slab) {
        const float* sl = red + ((size_t)slab * 64 + lane) * 32;
#pragma unroll
        for (int q = 0; q < 8; q++) {
            const int nt = q >> 2, rg = (q & 3) * 4;
            float4 v = *(const float4*)(sl + ((q + lane) & 7) * 4);
            acc[nt][rg] += v.x; acc[nt][rg+1] += v.y;
            acc[nt][rg+2] += v.z; acc[nt][rg+3] += v.w;
        }
    };
    if (kq >= 2) store_slab(mt * 2 + (kq - 2));
    __syncthreads();
    if (kq < 2) add_slab(mt * 2 + kq);
    __syncthreads();
    if (kq == 1) store_slab(mt);
    __syncthreads();
    if (kq == 0) add_slab(mt);
    __syncthreads();

    // ---- logits(+bias) -> LDS [64 tok][68]
    float* lg = (float*)(smem + 32768);
    if (kq == 0) {
        const int h = lane >> 5, c31 = lane & 31;
        const float bb0 = b[c31], bb1 = b[32 + c31];
#pragma unroll
        for (int nt = 0; nt < 2; nt++) {
#pragma unroll
            for (int e = 0; e < 16; e++) {
                const int r2 = (e & 3) + 8 * (e >> 2) + 4 * h;
                lg[(mt * 32 + r2) * 68 + nt * 32 + c31] = acc[nt][e] + (nt ? bb1 : bb0);
            }
        }
    }
    __syncthreads();

    // ---- top-2 + softmax + store (thread t = token)
    if (tid < TPB) {
        const float4* rowp = (const float4*)(lg + tid * 68);
        float v0 = -INFINITY, v1 = -INFINITY;
        int i0 = 0, i1 = 0;
#pragma unroll
        for (int q = 0; q < 16; q++) {
            float4 v4 = rowp[q];
            float vs[4] = {v4.x, v4.y, v4.z, v4.w};
#pragma unroll
            for (int j = 0; j < 4; j++) {
                const int e = q * 4 + j;
                const float v = vs[j];
                if (v > v0)      { v1 = v0; i1 = i0; v0 = v; i0 = e; }
                else if (v > v1) { v1 = v;  i1 = e; }
            }
        }
        const float e1 = expf(v1 - v0);     // v0 >= v1
        const float w0 = 1.f / (1.f + e1);
        const int tok = tok0 + tid;
        out[tok * 2 + 0] = w0;
        out[tok * 2 + 1] = e1 * w0;
        float* oi = out + (size_t)T * 2;    // indices chunk (float-cast)
        oi[tok * 2 + 0] = (float)i0;
        oi[tok * 2 + 1] = (float)i1;
    }
}

// Fallback (ws too small): R6 barrier-free kernel with in-loop W split.
__global__ __launch_bounds__(512, 4) void router_fb(
    const float* __restrict__ x, const float* __restrict__ W,
    const float* __restrict__ b, float* __restrict__ out, int T)
{
    __shared__ short smem[16384];
    const int tid = threadIdx.x;
    const int wv = tid >> 6, lane = tid & 63;
    const int tok0 = blockIdx.x * 32;
    const int row = lane & 31, kh = lane >> 5;
    const float* gx = x + (size_t)(tok0 + row) * D_MODEL + wv * 512 + kh * 8;
    f32x16 acc[2];
#pragma unroll
    for (int e = 0; e < 16; e++) { acc[0][e] = 0.f; acc[1][e] = 0.f; }
    for (int s = 0; s < 32; s++) {
        const float* g = gx + (size_t)s * 16;
        float4 xa = *(const float4*)g, xb = *(const float4*)(g + 4);
        const int k0 = wv * 512 + s * 16 + kh * 8;
        const float* w0 = W + (size_t)row * D_MODEL + k0;
        const float* w1 = W + (size_t)(32 + row) * D_MODEL + k0;
        short8 Ah, Al, B0h, B0l, B1h, B1l;
        split8(xa, xb, Ah, Al);
        split8(*(const float4*)w0, *(const float4*)(w0 + 4), B0h, B0l);
        split8(*(const float4*)w1, *(const float4*)(w1 + 4), B1h, B1l);
        MF(Ah, B0h, 0); MF(Ah, B0l, 0); MF(Al, B0h, 0); MF(Al, B0l, 0);
        MF(Ah, B1h, 1); MF(Ah, B1l, 1); MF(Al, B1h, 1); MF(Al, B1l, 1);
    }
    float* red = (float*)smem;
    auto store_slab = [&](int slab) {
        float* sl = red + ((size_t)slab * 64 + lane) * 32;
#pragma unroll
        for (int q = 0; q < 8; q++) {
            const int nt = q >> 2, rg = (q & 3) * 4;
            *(float4*)(sl + ((q + lane) & 7) * 4) =
                make_float4(acc[nt][rg], acc[nt][rg+1], acc[nt][rg+2], acc[nt][rg+3]);
        }
    };
    auto add_slab = [&](int slab) {
        const float* sl = red + ((size_t)slab * 64 + lane) * 32;
#pragma unroll
        for (int q = 0; q < 8; q++) {
            const int nt = q >> 2, rg = (q & 3) * 4;
            float4 v = *(const float4*)(sl + ((q + lane) & 7) * 4);
            acc[nt][rg] += v.x; acc[nt][rg+1] += v.y;
            acc[nt][rg+2] += v.z; acc[nt][rg+3] += v.w;
        }
    };
    __syncthreads();
    if (wv >= 4) store_slab(wv - 4);
    __syncthreads();
    if (wv < 4) add_slab(wv);
    __syncthreads();
    if (wv == 2 || wv == 3) store_slab(wv - 2);
    __syncthreads();
    if (wv < 2) add_slab(wv);
    __syncthreads();
    if (wv == 1) store_slab(0);
    __syncthreads();
    if (wv == 0) add_slab(0);
    __syncthreads();
    float* lg = (float*)smem;
    if (wv == 0) {
        const int h = lane >> 5, c31 = lane & 31;
        const float bb0 = b[c31], bb1 = b[32 + c31];
#pragma unroll
        for (int nt = 0; nt < 2; nt++)
#pragma unroll
            for (int e = 0; e < 16; e++) {
                const int r2 = (e & 3) + 8 * (e >> 2) + 4 * h;
                lg[r2 * 68 + nt * 32 + c31] = acc[nt][e] + (nt ? bb1 : bb0);
            }
    }
    __syncthreads();
    if (tid < 32) {
        const float4* rowp = (const float4*)(lg + tid * 68);
        float v0 = -INFINITY, v1 = -INFINITY;
        int i0 = 0, i1 = 0;
#pragma unroll
        for (int q = 0; q < 16; q++) {
            float4 v4 = rowp[q];
            float vs[4] = {v4.x, v4.y, v4.z, v4.w};
#pragma unroll
            for (int j = 0; j < 4; j++) {
                const float v = vs[j];
                if (v > v0)      { v1 = v0; i1 = i0; v0 = v; i0 = q*4+j; }
                else if (v > v1) { v1 = v;  i1 = q*4+j; }
            }
        }
        const float e1 = expf(v1 - v0);
        const float w0 = 1.f / (1.f + e1);
        const int tok = tok0 + tid;
        out[tok * 2 + 0] = w0;
        out[tok * 2 + 1] = e1 * w0;
        float* oi = out + (size_t)T * 2;
        oi[tok * 2 + 0] = (float)i0;
        oi[tok * 2 + 1] = (float)i1;
    }
}

extern "C" void kernel_launch(void* const* d_in, const int* in_sizes, int n_in,
                              void* d_out, int out_size, void* d_ws, size_t ws_size,
                              hipStream_t stream) {
    const float* x = (const float*)d_in[0];
    const float* W = (const float*)d_in[1];
    const float* b = (const float*)d_in[2];
    float* out = (float*)d_out;
    short* wsp = (short*)d_ws;
    const int T = in_sizes[0] / D_MODEL;     // 16384 tokens

    const bool pre = (ws_size >= (size_t)(2 * WS_SHORTS) * sizeof(short));  // 1 MB
    if (pre) {
        hipLaunchKernelGGL(wsplit_kernel, dim3(256), dim3(128), 0, stream, W, wsp);
        hipLaunchKernelGGL(router_pipe, dim3(T / TPB), dim3(512), 0, stream,
                           x, wsp, b, out, T);
    } else {
        hipLaunchKernelGGL(router_fb, dim3(T / 32), dim3(512), 0, stream,
                           x, W, b, out, T);
    }
}

// Round 15
// 64.825 us; speedup vs baseline: 1.0512x; 1.0512x over previous
//
#include <hip/hip_runtime.h>
#include <math.h>

#define D_MODEL 4096
#define NE 64
#define TPB 64                 // tokens per block
#define NSTEPS 16              // 4096 k / 256 k-per-step
#define XBUF 65536             // 64 KB per x buffer
#define WS_SHORTS (256 * 2 * 64 * 8)   // 262144 shorts per (hi|lo) region

typedef __attribute__((ext_vector_type(8))) short short8;
typedef __attribute__((ext_vector_type(16))) float f32x16;

__device__ __forceinline__ void gl_lds(const void* g, void* l) {
    __builtin_amdgcn_global_load_lds(
        (const __attribute__((address_space(1))) unsigned*)g,
        (__attribute__((address_space(3))) unsigned*)l, 16, 0, 0);
}

// Split 8 fp32 -> bf16 hi (RN) + bf16 lo (truncated residual), perm-packed.
__device__ __forceinline__ void split8(const float4& a, const float4& c,
                                       short8& h8, short8& l8) {
    union { short8 s; unsigned u[4]; } H, L;
    float vv[8] = {a.x, a.y, a.z, a.w, c.x, c.y, c.z, c.w};
#pragma unroll
    for (int p = 0; p < 4; p++) {
        const float v0 = vv[2*p], v1 = vv[2*p+1];
        const unsigned u0 = __float_as_uint(v0), u1 = __float_as_uint(v1);
        const unsigned r0 = u0 + 0x7fffu + ((u0 >> 16) & 1u);
        const unsigned r1 = u1 + 0x7fffu + ((u1 >> 16) & 1u);
        const float lo0 = v0 - __uint_as_float(r0 & 0xffff0000u);
        const float lo1 = v1 - __uint_as_float(r1 & 0xffff0000u);
        H.u[p] = __builtin_amdgcn_perm(r1, r0, 0x07060302u);
        L.u[p] = __builtin_amdgcn_perm(__float_as_uint(lo1),
                                       __float_as_uint(lo0), 0x07060302u);
    }
    h8 = H.s; l8 = L.s;
}

// Pre-split W -> ws bf16 hi/lo, fragment-linear:
// hi[((ck*2+nt)*64+l)*8+j] = bf16(W[nt*32+(l&31)][ck*16+(l>>5)*8+j]), lo at +WS_SHORTS
__global__ void wsplit_kernel(const float* __restrict__ W, short* __restrict__ wsp) {
    const int ck = blockIdx.x, t = threadIdx.x;
    const int nt = t >> 6, l = t & 63;
    const float* wp = W + (size_t)(nt * 32 + (l & 31)) * D_MODEL + ck * 16 + (l >> 5) * 8;
    float4 a = *(const float4*)wp, c = *(const float4*)(wp + 4);
    union { short8 s; unsigned u[4]; } H, L;
    float vv[8] = {a.x, a.y, a.z, a.w, c.x, c.y, c.z, c.w};
#pragma unroll
    for (int p = 0; p < 4; p++) {
        const float v0 = vv[2*p], v1 = vv[2*p+1];
        const unsigned u0 = __float_as_uint(v0), u1 = __float_as_uint(v1);
        const unsigned r0 = u0 + 0x7fffu + ((u0 >> 16) & 1u);
        const unsigned r1 = u1 + 0x7fffu + ((u1 >> 16) & 1u);
        const float lo0 = v0 - __uint_as_float(r0 & 0xffff0000u);
        const float lo1 = v1 - __uint_as_float(r1 & 0xffff0000u);
        const unsigned q0 = __float_as_uint(lo0) + 0x7fffu + ((__float_as_uint(lo0) >> 16) & 1u);
        const unsigned q1 = __float_as_uint(lo1) + 0x7fffu + ((__float_as_uint(lo1) >> 16) & 1u);
        H.u[p] = __builtin_amdgcn_perm(r1, r0, 0x07060302u);
        L.u[p] = __builtin_amdgcn_perm(q1, q0, 0x07060302u);
    }
    const size_t off = ((size_t)(ck * 2 + nt) * 64 + l) * 8;
    *(short8*)(wsp + off)             = H.s;
    *(short8*)(wsp + WS_SHORTS + off) = L.s;
}

#define MF(A_, B_, n_) acc[n_] = __builtin_amdgcn_mfma_f32_32x32x16_bf16( \
                             A_, B_, acc[n_], 0, 0, 0)

// K-step 256: 16 barrier events. 2 x 64 KB buffers, stage distance 1
// (stage issued post-BAR), W in regs as two 8-short8 halves per step.
// FIFO (steady state entering step s): [x(s)*8, WA(s)*8].
__global__ __launch_bounds__(512, 2) void router_pipe(
    const float* __restrict__ x, const short* __restrict__ wsp,
    const float* __restrict__ b, float* __restrict__ out, int T)
{
    __shared__ char smem[2 * XBUF];   // 128 KB; epilogue reuses

    const int tid  = threadIdx.x;
    const int wv   = tid >> 6, lane = tid & 63;
    const int mt   = wv & 1;          // token half-tile (rows mt*32..+32)
    const int kq   = wv >> 1;         // 64-k quarter of the 256-k step
    const int tok0 = blockIdx.x * TPB;

    // ---- staging (block-cooperative, page-local): wave w stages rows
    // w*4..w*4+3 (+32), 8 ops x 1KB blocks. Block (h,cb) holds
    // [row-in-group rg][slot clA]: logical 16B unit u = cb*16 + (clA^(rA&15)).
    const int rA  = wv * 4 + (lane >> 4);    // 0..31
    const int clA = lane & 15;
    const float* gx0 = x + (size_t)(tok0 + rA) * D_MODEL + ((clA ^ (rA & 15)) * 4);
    const float* gx1 = gx0 + (size_t)32 * D_MODEL;
    char* const stb = smem + wv * 8192;

#define STAGEX(s_, bi_) do { char* d_ = stb + (bi_) * XBUF;                    \
        const float* g0_ = gx0 + (s_) * 256;                                   \
        const float* g1_ = gx1 + (s_) * 256;                                   \
        gl_lds(g0_,       d_);        gl_lds(g0_ + 64,  d_ + 1024);            \
        gl_lds(g0_ + 128, d_ + 2048); gl_lds(g0_ + 192, d_ + 3072);            \
        gl_lds(g1_,       d_ + 4096); gl_lds(g1_ + 64,  d_ + 5120);            \
        gl_lds(g1_ + 128, d_ + 6144); gl_lds(g1_ + 192, d_ + 7168);            \
        __builtin_amdgcn_sched_barrier(0); } while (0)

    // W: one k16 chunk = 4 short8 {hi nt0, hi nt1, lo nt0, lo nt1}
#define LDW1(cg_, Wh0_, Wh1_, Wl0_, Wl1_) do {                                 \
        const size_t o0_ = (((size_t)(cg_) * 2 + 0) * 64 + lane) * 8;          \
        const size_t o1_ = (((size_t)(cg_) * 2 + 1) * 64 + lane) * 8;          \
        Wh0_ = *(const short8*)(wsp + o0_);                                    \
        Wh1_ = *(const short8*)(wsp + o1_);                                    \
        Wl0_ = *(const short8*)(wsp + WS_SHORTS + o0_);                        \
        Wl1_ = *(const short8*)(wsp + WS_SHORTS + o1_);                        \
    } while (0)
#define LDWH(cg_, P) do { LDW1((cg_), P##0h0, P##0h1, P##0l0, P##0l1);         \
        LDW1((cg_) + 1, P##1h0, P##1h1, P##1l0, P##1l1);                       \
        __builtin_amdgcn_sched_barrier(0); } while (0)

#define FENCE(n_) do { asm volatile("s_waitcnt vmcnt(" #n_ ")" ::: "memory");  \
        __builtin_amdgcn_sched_barrier(0); } while (0)
#define BAR do { __builtin_amdgcn_s_barrier();                                 \
        __builtin_amdgcn_sched_barrier(0); } while (0)

    f32x16 acc[2];
#pragma unroll
    for (int e = 0; e < 16; e++) { acc[0][e] = 0.f; acc[1][e] = 0.f; }

    // ---- compute-side read addressing (derivation):
    // row = mt*32+rw -> staging wave rw>>2, h=mt, rg=rw&3; unit u = ck16*4 +
    // khalf*2 + j with ck16 = kq*4+chunk -> u>>4 = kq, u&15 = 4*chunk+2*khalf+j;
    // slot = (u&15) ^ (rw&15).
    const int rw = lane & 31, khalf = lane >> 5;
    const int blane = (rw >> 2) * 8192 + (mt * 4 + kq) * 1024 + (rw & 3) * 256;
    const int swz = rw & 15;
#define XOFF(ch_, j_) ((((4 * (ch_) + 2 * khalf + (j_)) ^ swz)) * 16)
    const int o00 = XOFF(0, 0), o01 = XOFF(0, 1);
    const int o10 = XOFF(1, 0), o11 = XOFF(1, 1);
    const int o20 = XOFF(2, 0), o21 = XOFF(2, 1);
    const int o30 = XOFF(3, 0), o31 = XOFF(3, 1);

#define CCHUNK(bp_, oA_, oB_, Wh0_, Wh1_, Wl0_, Wl1_) do {                     \
        float4 xa_ = *(const float4*)((bp_) + oA_);                            \
        float4 xb_ = *(const float4*)((bp_) + oB_);                            \
        short8 Ah_, Al_; split8(xa_, xb_, Ah_, Al_);                           \
        MF(Ah_, Wh0_, 0); MF(Ah_, Wl0_, 0); MF(Al_, Wh0_, 0); MF(Al_, Wl0_, 0);\
        MF(Ah_, Wh1_, 1); MF(Ah_, Wl1_, 1); MF(Al_, Wh1_, 1); MF(Al_, Wl1_, 1);\
    } while (0)

#define COMPA(bi_) do { const char* bp_ = smem + (bi_) * XBUF + blane;         \
        CCHUNK(bp_, o00, o01, A0h0, A0h1, A0l0, A0l1);                         \
        CCHUNK(bp_, o10, o11, A1h0, A1h1, A1l0, A1l1); } while (0)
#define COMPB(bi_) do { const char* bp_ = smem + (bi_) * XBUF + blane;         \
        CCHUNK(bp_, o20, o21, B0h0, B0h1, B0l0, B0l1);                         \
        CCHUNK(bp_, o30, o31, B1h0, B1h1, B1l0, B1l1); } while (0)

    short8 A0h0, A0h1, A0l0, A0l1, A1h0, A1h1, A1l0, A1l1;
    short8 B0h0, B0h1, B0l0, B0l1, B1h0, B1h1, B1l0, B1l1;

    // prologue: x(0) -> buf0, WA(0). Queue: [x(0)*8, WA(0)*8]
    STAGEX(0, 0);
    LDWH(0 * 16 + kq * 4, A);

    for (int s = 0; s < NSTEPS - 1; ++s) {
        const int cg = s * 16 + kq * 4;
        LDWH(cg + 2, B);               // WB(s): queue -> 24
        FENCE(8);                      // drain x(s)+WA(s); keep WB(s)
        BAR;                           // all waves' x(s) landed; buf (s+1)&1 free
        STAGEX(s + 1, (s + 1) & 1);    // queue -> 16
        COMPA(s & 1);
        LDWH(cg + 16, A);              // WA(s+1): queue -> 24
        FENCE(16);                     // drain WB(s); keep x(s+1)+WA(s+1)
        COMPB(s & 1);
    }
    // tail: s = NSTEPS-1. Queue entering: [x(s)*8, WA(s)*8]
    {
        const int s = NSTEPS - 1;
        LDWH(s * 16 + kq * 4 + 2, B);
        FENCE(8);
        BAR;
        COMPA(s & 1);
        FENCE(0);
        COMPB(s & 1);
    }

    __syncthreads();

    // ---- reduce 4 k-quarters per mt (2 rounds, rotate-swizzled slabs; 32 KB)
    float* red = (float*)smem;
    auto store_slab = [&](int slab) {
        float* sl = red + ((size_t)slab * 64 + lane) * 32;
#pragma unroll
        for (int q = 0; q < 8; q++) {
            const int nt = q >> 2, rg = (q & 3) * 4;
            *(float4*)(sl + ((q + lane) & 7) * 4) =
                make_float4(acc[nt][rg], acc[nt][rg+1], acc[nt][rg+2], acc[nt][rg+3]);
        }
    };
    auto add_slab = [&](int slab) {
        const float* sl = red + ((size_t)slab * 64 + lane) * 32;
#pragma unroll
        for (int q = 0; q < 8; q++) {
            const int nt = q >> 2, rg = (q & 3) * 4;
            float4 v = *(const float4*)(sl + ((q + lane) & 7) * 4);
            acc[nt][rg] += v.x; acc[nt][rg+1] += v.y;
            acc[nt][rg+2] += v.z; acc[nt][rg+3] += v.w;
        }
    };
    if (kq >= 2) store_slab(mt * 2 + (kq - 2));
    __syncthreads();
    if (kq < 2) add_slab(mt * 2 + kq);
    __syncthreads();
    if (kq == 1) store_slab(mt);
    __syncthreads();
    if (kq == 0) add_slab(mt);
    __syncthreads();

    // ---- logits(+bias) -> LDS [64 tok][68]
    float* lg = (float*)(smem + 32768);
    if (kq == 0) {
        const int h = lane >> 5, c31 = lane & 31;
        const float bb0 = b[c31], bb1 = b[32 + c31];
#pragma unroll
        for (int nt = 0; nt < 2; nt++) {
#pragma unroll
            for (int e = 0; e < 16; e++) {
                const int r2 = (e & 3) + 8 * (e >> 2) + 4 * h;
                lg[(mt * 32 + r2) * 68 + nt * 32 + c31] = acc[nt][e] + (nt ? bb1 : bb0);
            }
        }
    }
    __syncthreads();

    // ---- top-2 + softmax + store (thread t = token)
    if (tid < TPB) {
        const float4* rowp = (const float4*)(lg + tid * 68);
        float v0 = -INFINITY, v1 = -INFINITY;
        int i0 = 0, i1 = 0;
#pragma unroll
        for (int q = 0; q < 16; q++) {
            float4 v4 = rowp[q];
            float vs[4] = {v4.x, v4.y, v4.z, v4.w};
#pragma unroll
            for (int j = 0; j < 4; j++) {
                const int e = q * 4 + j;
                const float v = vs[j];
                if (v > v0)      { v1 = v0; i1 = i0; v0 = v; i0 = e; }
                else if (v > v1) { v1 = v;  i1 = e; }
            }
        }
        const float e1 = expf(v1 - v0);     // v0 >= v1
        const float w0 = 1.f / (1.f + e1);
        const int tok = tok0 + tid;
        out[tok * 2 + 0] = w0;
        out[tok * 2 + 1] = e1 * w0;
        float* oi = out + (size_t)T * 2;    // indices chunk (float-cast)
        oi[tok * 2 + 0] = (float)i0;
        oi[tok * 2 + 1] = (float)i1;
    }
}

// Fallback (ws too small): R6 barrier-free kernel with in-loop W split.
__global__ __launch_bounds__(512, 4) void router_fb(
    const float* __restrict__ x, const float* __restrict__ W,
    const float* __restrict__ b, float* __restrict__ out, int T)
{
    __shared__ short smem[16384];
    const int tid = threadIdx.x;
    const int wv = tid >> 6, lane = tid & 63;
    const int tok0 = blockIdx.x * 32;
    const int row = lane & 31, kh = lane >> 5;
    const float* gx = x + (size_t)(tok0 + row) * D_MODEL + wv * 512 + kh * 8;
    f32x16 acc[2];
#pragma unroll
    for (int e = 0; e < 16; e++) { acc[0][e] = 0.f; acc[1][e] = 0.f; }
    for (int s = 0; s < 32; s++) {
        const float* g = gx + (size_t)s * 16;
        float4 xa = *(const float4*)g, xb = *(const float4*)(g + 4);
        const int k0 = wv * 512 + s * 16 + kh * 8;
        const float* w0 = W + (size_t)row * D_MODEL + k0;
        const float* w1 = W + (size_t)(32 + row) * D_MODEL + k0;
        short8 Ah, Al, B0h, B0l, B1h, B1l;
        split8(xa, xb, Ah, Al);
        split8(*(const float4*)w0, *(const float4*)(w0 + 4), B0h, B0l);
        split8(*(const float4*)w1, *(const float4*)(w1 + 4), B1h, B1l);
        MF(Ah, B0h, 0); MF(Ah, B0l, 0); MF(Al, B0h, 0); MF(Al, B0l, 0);
        MF(Ah, B1h, 1); MF(Ah, B1l, 1); MF(Al, B1h, 1); MF(Al, B1l, 1);
    }
    float* red = (float*)smem;
    auto store_slab = [&](int slab) {
        float* sl = red + ((size_t)slab * 64 + lane) * 32;
#pragma unroll
        for (int q = 0; q < 8; q++) {
            const int nt = q >> 2, rg = (q & 3) * 4;
            *(float4*)(sl + ((q + lane) & 7) * 4) =
                make_float4(acc[nt][rg], acc[nt][rg+1], acc[nt][rg+2], acc[nt][rg+3]);
        }
    };
    auto add_slab = [&](int slab) {
        const float* sl = red + ((size_t)slab * 64 + lane) * 32;
#pragma unroll
        for (int q = 0; q < 8; q++) {
            const int nt = q >> 2, rg = (q & 3) * 4;
            float4 v = *(const float4*)(sl + ((q + lane) & 7) * 4);
            acc[nt][rg] += v.x; acc[nt][rg+1] += v.y;
            acc[nt][rg+2] += v.z; acc[nt][rg+3] += v.w;
        }
    };
    __syncthreads();
    if (wv >= 4) store_slab(wv - 4);
    __syncthreads();
    if (wv < 4) add_slab(wv);
    __syncthreads();
    if (wv == 2 || wv == 3) store_slab(wv - 2);
    __syncthreads();
    if (wv < 2) add_slab(wv);
    __syncthreads();
    if (wv == 1) store_slab(0);
    __syncthreads();
    if (wv == 0) add_slab(0);
    __syncthreads();
    float* lg = (float*)smem;
    if (wv == 0) {
        const int h = lane >> 5, c31 = lane & 31;
        const float bb0 = b[c31], bb1 = b[32 + c31];
#pragma unroll
        for (int nt = 0; nt < 2; nt++)
#pragma unroll
            for (int e = 0; e < 16; e++) {
                const int r2 = (e & 3) + 8 * (e >> 2) + 4 * h;
                lg[r2 * 68 + nt * 32 + c31] = acc[nt][e] + (nt ? bb1 : bb0);
            }
    }
    __syncthreads();
    if (tid < 32) {
        const float4* rowp = (const float4*)(lg + tid * 68);
        float v0 = -INFINITY, v1 = -INFINITY;
        int i0 = 0, i1 = 0;
#pragma unroll
        for (int q = 0; q < 16; q++) {
            float4 v4 = rowp[q];
            float vs[4] = {v4.x, v4.y, v4.z, v4.w};
#pragma unroll
            for (int j = 0; j < 4; j++) {
                const float v = vs[j];
                if (v > v0)      { v1 = v0; i1 = i0; v0 = v; i0 = q*4+j; }
                else if (v > v1) { v1 = v;  i1 = q*4+j; }
            }
        }
        const float e1 = expf(v1 - v0);
        const float w0 = 1.f / (1.f + e1);
        const int tok = tok0 + tid;
        out[tok * 2 + 0] = w0;
        out[tok * 2 + 1] = e1 * w0;
        float* oi = out + (size_t)T * 2;
        oi[tok * 2 + 0] = (float)i0;
        oi[tok * 2 + 1] = (float)i1;
    }
}

extern "C" void kernel_launch(void* const* d_in, const int* in_sizes, int n_in,
                              void* d_out, int out_size, void* d_ws, size_t ws_size,
                              hipStream_t stream) {
    const float* x = (const float*)d_in[0];
    const float* W = (const float*)d_in[1];
    const float* b = (const float*)d_in[2];
    float* out = (float*)d_out;
    short* wsp = (short*)d_ws;
    const int T = in_sizes[0] / D_MODEL;     // 16384 tokens

    const bool pre = (ws_size >= (size_t)(2 * WS_SHORTS) * sizeof(short));  // 1 MB
    if (pre) {
        hipLaunchKernelGGL(wsplit_kernel, dim3(256), dim3(128), 0, stream, W, wsp);
        hipLaunchKernelGGL(router_pipe, dim3(T / TPB), dim3(512), 0, stream,
                           x, wsp, b, out, T);
    } else {
        hipLaunchKernelGGL(router_fb, dim3(T / 32), dim3(512), 0, stream,
                           x, W, b, out, T);
    }
}

// Round 16
// 64.165 us; speedup vs baseline: 1.0620x; 1.0103x over previous
//
#include <hip/hip_runtime.h>
#include <math.h>

#define D_MODEL 4096
#define NE 64
#define TPB 64                 // tokens per block
#define NSTEPS 32              // 4096 k / 128 k-per-step
#define XBUF 32768             // bytes per x LDS buffer (2 halves x 16 KB)
#define NXBUF 4                // 128 KB ring
#define WS_SHORTS (256 * 2 * 64 * 8)   // 262144 shorts per (hi|lo) region

typedef __attribute__((ext_vector_type(8))) short short8;
typedef __attribute__((ext_vector_type(16))) float f32x16;

__device__ __forceinline__ void gl_lds(const void* g, void* l) {
    __builtin_amdgcn_global_load_lds(
        (const __attribute__((address_space(1))) unsigned*)g,
        (__attribute__((address_space(3))) unsigned*)l, 16, 0, 0);
}

// Split 8 fp32 -> bf16 hi (RN) + bf16 lo (truncated residual), perm-packed.
__device__ __forceinline__ void split8(const float4& a, const float4& c,
                                       short8& h8, short8& l8) {
    union { short8 s; unsigned u[4]; } H, L;
    float vv[8] = {a.x, a.y, a.z, a.w, c.x, c.y, c.z, c.w};
#pragma unroll
    for (int p = 0; p < 4; p++) {
        const float v0 = vv[2*p], v1 = vv[2*p+1];
        const unsigned u0 = __float_as_uint(v0), u1 = __float_as_uint(v1);
        const unsigned r0 = u0 + 0x7fffu + ((u0 >> 16) & 1u);
        const unsigned r1 = u1 + 0x7fffu + ((u1 >> 16) & 1u);
        const float lo0 = v0 - __uint_as_float(r0 & 0xffff0000u);
        const float lo1 = v1 - __uint_as_float(r1 & 0xffff0000u);
        H.u[p] = __builtin_amdgcn_perm(r1, r0, 0x07060302u);
        L.u[p] = __builtin_amdgcn_perm(__float_as_uint(lo1),
                                       __float_as_uint(lo0), 0x07060302u);
    }
    h8 = H.s; l8 = L.s;
}

// Pre-split W -> ws bf16 hi/lo, fragment-linear:
// hi[((ck*2+nt)*64+l)*8+j] = bf16(W[nt*32+(l&31)][ck*16+(l>>5)*8+j]), lo at +WS_SHORTS
__global__ void wsplit_kernel(const float* __restrict__ W, short* __restrict__ wsp) {
    const int ck = blockIdx.x, t = threadIdx.x;
    const int nt = t >> 6, l = t & 63;
    const float* wp = W + (size_t)(nt * 32 + (l & 31)) * D_MODEL + ck * 16 + (l >> 5) * 8;
    float4 a = *(const float4*)wp, c = *(const float4*)(wp + 4);
    union { short8 s; unsigned u[4]; } H, L;
    float vv[8] = {a.x, a.y, a.z, a.w, c.x, c.y, c.z, c.w};
#pragma unroll
    for (int p = 0; p < 4; p++) {
        const float v0 = vv[2*p], v1 = vv[2*p+1];
        const unsigned u0 = __float_as_uint(v0), u1 = __float_as_uint(v1);
        const unsigned r0 = u0 + 0x7fffu + ((u0 >> 16) & 1u);
        const unsigned r1 = u1 + 0x7fffu + ((u1 >> 16) & 1u);
        const float lo0 = v0 - __uint_as_float(r0 & 0xffff0000u);
        const float lo1 = v1 - __uint_as_float(r1 & 0xffff0000u);
        const unsigned q0 = __float_as_uint(lo0) + 0x7fffu + ((__float_as_uint(lo0) >> 16) & 1u);
        const unsigned q1 = __float_as_uint(lo1) + 0x7fffu + ((__float_as_uint(lo1) >> 16) & 1u);
        H.u[p] = __builtin_amdgcn_perm(r1, r0, 0x07060302u);
        L.u[p] = __builtin_amdgcn_perm(q1, q0, 0x07060302u);
    }
    const size_t off = ((size_t)(ck * 2 + nt) * 64 + l) * 8;
    *(short8*)(wsp + off)             = H.s;
    *(short8*)(wsp + WS_SHORTS + off) = L.s;
}

#define MF(A_, B_, n_) acc[n_] = __builtin_amdgcn_mfma_f32_32x32x16_bf16( \
                             A_, B_, acc[n_], 0, 0, 0)

// R13 base + segment-2 loop: ONE barrier per 2 steps (16 total), same 4-buffer
// ring and distance-2 stage window. FIFO invariant entering each segment:
// [W(t)*8, W(t+1)*8] = 16 outstanding.
__global__ __launch_bounds__(512, 2) void router_pipe(
    const float* __restrict__ x, const short* __restrict__ wsp,
    const float* __restrict__ b, float* __restrict__ out, int T)
{
    __shared__ char smem[NXBUF * XBUF];   // 128 KB x ring; epilogue reuses

    const int tid  = threadIdx.x;
    const int wv   = tid >> 6, lane = tid & 63;
    const int mt   = wv & 1;          // token half-tile
    const int kq   = wv >> 1;         // 32-k quarter of the 128-k step
    const int tok0 = blockIdx.x * TPB;

    // x staging: thread t -> (tokA = t>>4, clA = t&15), XOR-swizzled chunk col.
    const int tokA = tid >> 4, clA = tid & 15;
    const int tokB = 32 + tokA;
    const float* gx1 = x + (size_t)(tok0 + tokA) * D_MODEL + ((clA ^ (tokA & 15)) * 4);
    const float* gx2 = x + (size_t)(tok0 + tokB) * D_MODEL + ((clA ^ (tokB & 15)) * 4);

#define STAGEX(s_, bi_) do { char* db_ = smem + (bi_) * XBUF + wv * 1024;      \
        gl_lds(gx1 + (size_t)(s_) * 128,      db_);                            \
        gl_lds(gx2 + (size_t)(s_) * 128,      db_ + 8192);                     \
        gl_lds(gx1 + (size_t)(s_) * 128 + 64, db_ + 16384);                    \
        gl_lds(gx2 + (size_t)(s_) * 128 + 64, db_ + 24576);                    \
        __builtin_amdgcn_sched_barrier(0); } while (0)

#define LDW(s_, W0_,W1_,W2_,W3_,W4_,W5_,W6_,W7_) do {                          \
        const size_t cg0_ = (size_t)(s_) * 8 + kq * 2;                         \
        const size_t a0_ = ((cg0_ * 2 + 0) * 64 + lane) * 8;                   \
        const size_t a1_ = ((cg0_ * 2 + 1) * 64 + lane) * 8;                   \
        const size_t a2_ = (((cg0_ + 1) * 2 + 0) * 64 + lane) * 8;             \
        const size_t a3_ = (((cg0_ + 1) * 2 + 1) * 64 + lane) * 8;             \
        W0_ = *(const short8*)(wsp + a0_);                                     \
        W1_ = *(const short8*)(wsp + a1_);                                     \
        W2_ = *(const short8*)(wsp + WS_SHORTS + a0_);                         \
        W3_ = *(const short8*)(wsp + WS_SHORTS + a1_);                         \
        W4_ = *(const short8*)(wsp + a2_);                                     \
        W5_ = *(const short8*)(wsp + a3_);                                     \
        W6_ = *(const short8*)(wsp + WS_SHORTS + a2_);                         \
        W7_ = *(const short8*)(wsp + WS_SHORTS + a3_);                         \
        __builtin_amdgcn_sched_barrier(0); } while (0)

#define FENCE(n_) do { asm volatile("s_waitcnt vmcnt(" #n_ ")" ::: "memory");  \
        __builtin_amdgcn_sched_barrier(0); } while (0)
#define BAR do { __builtin_amdgcn_s_barrier();                                 \
        __builtin_amdgcn_sched_barrier(0); } while (0)

    f32x16 acc[2];
#pragma unroll
    for (int e = 0; e < 16; e++) { acc[0][e] = 0.f; acc[1][e] = 0.f; }

    // fragment read offsets (bytes within an x buffer)
    const int row = mt * 32 + (lane & 31);
    const int cA  = kq * 8 + (lane >> 5) * 2;        // ck=0 chunks cA, cA+1
#define XOFF(c_) (((c_) >> 4) * 16384 + row * 256 + ((((c_) & 15) ^ (row & 15)) * 16))
    const int xoA0 = XOFF(cA),     xoA1 = XOFF(cA + 1);
    const int xoB0 = XOFF(cA + 4), xoB1 = XOFF(cA + 5);   // ck=1

#define COMPUTE(bi_, W0_,W1_,W2_,W3_,W4_,W5_,W6_,W7_) do {                     \
        const char* buf_ = smem + (bi_) * XBUF;                                \
        { float4 xa_ = *(const float4*)(buf_ + xoA0);                          \
          float4 xb_ = *(const float4*)(buf_ + xoA1);                          \
          short8 Ah_, Al_; split8(xa_, xb_, Ah_, Al_);                         \
          MF(Ah_, W0_, 0); MF(Ah_, W2_, 0); MF(Al_, W0_, 0); MF(Al_, W2_, 0);  \
          MF(Ah_, W1_, 1); MF(Ah_, W3_, 1); MF(Al_, W1_, 1); MF(Al_, W3_, 1); }\
        { float4 xa_ = *(const float4*)(buf_ + xoB0);                          \
          float4 xb_ = *(const float4*)(buf_ + xoB1);                          \
          short8 Ah_, Al_; split8(xa_, xb_, Ah_, Al_);                         \
          MF(Ah_, W4_, 0); MF(Ah_, W6_, 0); MF(Al_, W4_, 0); MF(Al_, W6_, 0);  \
          MF(Ah_, W5_, 1); MF(Ah_, W7_, 1); MF(Al_, W5_, 1); MF(Al_, W7_, 1); }\
        } while (0)

    short8 Wa0, Wa1, Wa2, Wa3, Wa4, Wa5, Wa6, Wa7;
    short8 Wb0, Wb1, Wb2, Wb3, Wb4, Wb5, Wb6, Wb7;

    // prologue: FIFO after issue = [x0*4, x1*4, W0*8, W1*8]
    STAGEX(0, 0); STAGEX(1, 1);
    LDW(0, Wa0,Wa1,Wa2,Wa3,Wa4,Wa5,Wa6,Wa7);
    LDW(1, Wb0,Wb1,Wb2,Wb3,Wb4,Wb5,Wb6,Wb7);
    FENCE(16);                  // drains x0,x1; keeps [W0*8, W1*8] = invariant
    BAR;                        // bufs 0,1 ready block-wide

    for (int t = 0; t < NSTEPS - 2; t += 2) {
        // entering: [W(t)*8, W(t+1)*8] = 16 outstanding
        STAGEX(t + 2, (t + 2) & 3);
        STAGEX(t + 3, (t + 3) & 3);            // -> 24
        FENCE(16);                             // drains W(t)
        COMPUTE(t & 3, Wa0,Wa1,Wa2,Wa3,Wa4,Wa5,Wa6,Wa7);
        LDW(t + 2, Wa0,Wa1,Wa2,Wa3,Wa4,Wa5,Wa6,Wa7);   // -> 24
        FENCE(16);                             // drains W(t+1)
        COMPUTE((t + 1) & 3, Wb0,Wb1,Wb2,Wb3,Wb4,Wb5,Wb6,Wb7);
        LDW(t + 3, Wb0,Wb1,Wb2,Wb3,Wb4,Wb5,Wb6,Wb7);   // -> 24
        FENCE(16);                             // drains x(t+2), x(t+3)
        BAR;                                   // bufs t+2,t+3 ready block-wide
    }
    // tail (t = NSTEPS-2): entering FIFO = [W(30)*8, W(31)*8]
    FENCE(8);                                  // drains W(30)
    COMPUTE((NSTEPS - 2) & 3, Wa0,Wa1,Wa2,Wa3,Wa4,Wa5,Wa6,Wa7);
    FENCE(0);                                  // drains W(31)
    COMPUTE((NSTEPS - 1) & 3, Wb0,Wb1,Wb2,Wb3,Wb4,Wb5,Wb6,Wb7);

    __syncthreads();

    // ---- reduce 4 k-quarters per mt (2 rounds, rotate-swizzled slabs; 32 KB)
    float* red = (float*)smem;
    auto store_slab = [&](int slab) {
        float* sl = red + ((size_t)slab * 64 + lane) * 32;
#pragma unroll
        for (int q = 0; q < 8; q++) {
            const int nt = q >> 2, rg = (q & 3) * 4;
            *(float4*)(sl + ((q + lane) & 7) * 4) =
                make_float4(acc[nt][rg], acc[nt][rg+1], acc[nt][rg+2], acc[nt][rg+3]);
        }
    };
    auto add_slab = [&](int slab) {
        const float* sl = red + ((size_t)slab * 64 + lane) * 32;
#pragma unroll
        for (int q = 0; q < 8; q++) {
            const int nt = q >> 2, rg = (q & 3) * 4;
            float4 v = *(const float4*)(sl + ((q + lane) & 7) * 4);
            acc[nt][rg] += v.x; acc[nt][rg+1] += v.y;
            acc[nt][rg+2] += v.z; acc[nt][rg+3] += v.w;
        }
    };
    if (kq >= 2) store_slab(mt * 2 + (kq - 2));
    __syncthreads();
    if (kq < 2) add_slab(mt * 2 + kq);
    __syncthreads();
    if (kq == 1) store_slab(mt);
    __syncthreads();
    if (kq == 0) add_slab(mt);
    __syncthreads();

    // ---- logits(+bias) -> LDS [64 tok][68]
    float* lg = (float*)(smem + 32768);
    if (kq == 0) {
        const int h = lane >> 5, c31 = lane & 31;
        const float bb0 = b[c31], bb1 = b[32 + c31];
#pragma unroll
        for (int nt = 0; nt < 2; nt++) {
#pragma unroll
            for (int e = 0; e < 16; e++) {
                const int r2 = (e & 3) + 8 * (e >> 2) + 4 * h;
                lg[(mt * 32 + r2) * 68 + nt * 32 + c31] = acc[nt][e] + (nt ? bb1 : bb0);
            }
        }
    }
    __syncthreads();

    // ---- top-2 + softmax + store (thread t = token)
    if (tid < TPB) {
        const float4* rowp = (const float4*)(lg + tid * 68);
        float v0 = -INFINITY, v1 = -INFINITY;
        int i0 = 0, i1 = 0;
#pragma unroll
        for (int q = 0; q < 16; q++) {
            float4 v4 = rowp[q];
            float vs[4] = {v4.x, v4.y, v4.z, v4.w};
#pragma unroll
            for (int j = 0; j < 4; j++) {
                const int e = q * 4 + j;
                const float v = vs[j];
                if (v > v0)      { v1 = v0; i1 = i0; v0 = v; i0 = e; }
                else if (v > v1) { v1 = v;  i1 = e; }
            }
        }
        const float e1 = expf(v1 - v0);     // v0 >= v1
        const float w0 = 1.f / (1.f + e1);
        const int tok = tok0 + tid;
        out[tok * 2 + 0] = w0;
        out[tok * 2 + 1] = e1 * w0;
        float* oi = out + (size_t)T * 2;    // indices chunk (float-cast)
        oi[tok * 2 + 0] = (float)i0;
        oi[tok * 2 + 1] = (float)i1;
    }
}

// Fallback (ws too small): R6 barrier-free kernel with in-loop W split.
__global__ __launch_bounds__(512, 4) void router_fb(
    const float* __restrict__ x, const float* __restrict__ W,
    const float* __restrict__ b, float* __restrict__ out, int T)
{
    __shared__ short smem[16384];
    const int tid = threadIdx.x;
    const int wv = tid >> 6, lane = tid & 63;
    const int tok0 = blockIdx.x * 32;
    const int row = lane & 31, kh = lane >> 5;
    const float* gx = x + (size_t)(tok0 + row) * D_MODEL + wv * 512 + kh * 8;
    f32x16 acc[2];
#pragma unroll
    for (int e = 0; e < 16; e++) { acc[0][e] = 0.f; acc[1][e] = 0.f; }
    for (int s = 0; s < 32; s++) {
        const float* g = gx + (size_t)s * 16;
        float4 xa = *(const float4*)g, xb = *(const float4*)(g + 4);
        const int k0 = wv * 512 + s * 16 + kh * 8;
        const float* w0 = W + (size_t)row * D_MODEL + k0;
        const float* w1 = W + (size_t)(32 + row) * D_MODEL + k0;
        short8 Ah, Al, B0h, B0l, B1h, B1l;
        split8(xa, xb, Ah, Al);
        split8(*(const float4*)w0, *(const float4*)(w0 + 4), B0h, B0l);
        split8(*(const float4*)w1, *(const float4*)(w1 + 4), B1h, B1l);
        MF(Ah, B0h, 0); MF(Ah, B0l, 0); MF(Al, B0h, 0); MF(Al, B0l, 0);
        MF(Ah, B1h, 1); MF(Ah, B1l, 1); MF(Al, B1h, 1); MF(Al, B1l, 1);
    }
    float* red = (float*)smem;
    auto store_slab = [&](int slab) {
        float* sl = red + ((size_t)slab * 64 + lane) * 32;
#pragma unroll
        for (int q = 0; q < 8; q++) {
            const int nt = q >> 2, rg = (q & 3) * 4;
            *(float4*)(sl + ((q + lane) & 7) * 4) =
                make_float4(acc[nt][rg], acc[nt][rg+1], acc[nt][rg+2], acc[nt][rg+3]);
        }
    };
    auto add_slab = [&](int slab) {
        const float* sl = red + ((size_t)slab * 64 + lane) * 32;
#pragma unroll
        for (int q = 0; q < 8; q++) {
            const int nt = q >> 2, rg = (q & 3) * 4;
            float4 v = *(const float4*)(sl + ((q + lane) & 7) * 4);
            acc[nt][rg] += v.x; acc[nt][rg+1] += v.y;
            acc[nt][rg+2] += v.z; acc[nt][rg+3] += v.w;
        }
    };
    __syncthreads();
    if (wv >= 4) store_slab(wv - 4);
    __syncthreads();
    if (wv < 4) add_slab(wv);
    __syncthreads();
    if (wv == 2 || wv == 3) store_slab(wv - 2);
    __syncthreads();
    if (wv < 2) add_slab(wv);
    __syncthreads();
    if (wv == 1) store_slab(0);
    __syncthreads();
    if (wv == 0) add_slab(0);
    __syncthreads();
    float* lg = (float*)smem;
    if (wv == 0) {
        const int h = lane >> 5, c31 = lane & 31;
        const float bb0 = b[c31], bb1 = b[32 + c31];
#pragma unroll
        for (int nt = 0; nt < 2; nt++)
#pragma unroll
            for (int e = 0; e < 16; e++) {
                const int r2 = (e & 3) + 8 * (e >> 2) + 4 * h;
                lg[r2 * 68 + nt * 32 + c31] = acc[nt][e] + (nt ? bb1 : bb0);
            }
    }
    __syncthreads();
    if (tid < 32) {
        const float4* rowp = (const float4*)(lg + tid * 68);
        float v0 = -INFINITY, v1 = -INFINITY;
        int i0 = 0, i1 = 0;
#pragma unroll
        for (int q = 0; q < 16; q++) {
            float4 v4 = rowp[q];
            float vs[4] = {v4.x, v4.y, v4.z, v4.w};
#pragma unroll
            for (int j = 0; j < 4; j++) {
                const float v = vs[j];
                if (v > v0)      { v1 = v0; i1 = i0; v0 = v; i0 = q*4+j; }
                else if (v > v1) { v1 = v;  i1 = q*4+j; }
            }
        }
        const float e1 = expf(v1 - v0);
        const float w0 = 1.f / (1.f + e1);
        const int tok = tok0 + tid;
        out[tok * 2 + 0] = w0;
        out[tok * 2 + 1] = e1 * w0;
        float* oi = out + (size_t)T * 2;
        oi[tok * 2 + 0] = (float)i0;
        oi[tok * 2 + 1] = (float)i1;
    }
}

extern "C" void kernel_launch(void* const* d_in, const int* in_sizes, int n_in,
                              void* d_out, int out_size, void* d_ws, size_t ws_size,
                              hipStream_t stream) {
    const float* x = (const float*)d_in[0];
    const float* W = (const float*)d_in[1];
    const float* b = (const float*)d_in[2];
    float* out = (float*)d_out;
    short* wsp = (short*)d_ws;
    const int T = in_sizes[0] / D_MODEL;     // 16384 tokens

    const bool pre = (ws_size >= (size_t)(2 * WS_SHORTS) * sizeof(short));  // 1 MB
    if (pre) {
        hipLaunchKernelGGL(wsplit_kernel, dim3(256), dim3(128), 0, stream, W, wsp);
        hipLaunchKernelGGL(router_pipe, dim3(T / TPB), dim3(512), 0, stream,
                           x, wsp, b, out, T);
    } else {
        hipLaunchKernelGGL(router_fb, dim3(T / 32), dim3(512), 0, stream,
                           x, W, b, out, T);
    }
}